// Round 1
// baseline (419.381 us; speedup 1.0000x reference)
//
#include <hip/hip_runtime.h>
#include <hip/hip_bf16.h>

#define N_TOK 2048
#define DIM_  2048
#define HID_  1024
#define NEXP  8
#define NSLOT 4096          // N_TOK * K
#define TSLOT 6144          // + shared-expert slots
#define BM 128
#define BN 64
#define BK 32
#define LDA 40              // BK + 8 pad (80B row stride -> ~2-way LDS conflicts, free)
#define MAX_TILES 56

typedef unsigned short u16;
typedef __attribute__((ext_vector_type(4))) float f32x4;
typedef __attribute__((ext_vector_type(8))) __bf16 bf16x8;

static __device__ __forceinline__ u16 f2b(float f) {
  unsigned u = __builtin_bit_cast(unsigned, f);
  u += 0x7fffu + ((u >> 16) & 1u);   // RNE
  return (u16)(u >> 16);
}

// ---------------- fp32 -> bf16 bulk convert ----------------
__global__ __launch_bounds__(256) void cvt_kernel(const float* __restrict__ src,
                                                  u16* __restrict__ dst, int n4) {
  int i = blockIdx.x * 256 + threadIdx.x;
  int stride = gridDim.x * 256;
  for (; i < n4; i += stride) {
    float4 v = ((const float4*)src)[i];
    ushort4 o;
    o.x = f2b(v.x); o.y = f2b(v.y); o.z = f2b(v.z); o.w = f2b(v.w);
    ((ushort4*)dst)[i] = o;
  }
}

// ---------------- router: logits, top-2, counts ----------------
__global__ __launch_bounds__(256) void router_kernel(const float* __restrict__ x,
                                                     const float* __restrict__ gw,
                                                     int* __restrict__ sel_flat,
                                                     float* __restrict__ score_flat,
                                                     int* __restrict__ counts) {
  int n = blockIdx.x;
  const float* xr = x + (size_t)n * DIM_;
  int lane = threadIdx.x & 63, wid = threadIdx.x >> 6;
  __shared__ float s_logit[NEXP];
#pragma unroll
  for (int ee = 0; ee < 2; ++ee) {
    int e = wid * 2 + ee;
    const float* g = gw + (size_t)e * DIM_;
    float p = 0.f;
    for (int d = lane; d < DIM_; d += 64) p += xr[d] * g[d];
#pragma unroll
    for (int off = 32; off; off >>= 1) p += __shfl_down(p, off, 64);
    if (lane == 0) s_logit[e] = p;
  }
  __syncthreads();
  if (threadIdx.x == 0) {
    int b0 = 0; float v0 = s_logit[0];
    for (int e = 1; e < NEXP; ++e) if (s_logit[e] > v0) { v0 = s_logit[e]; b0 = e; }
    int b1 = -1; float v1 = -1e30f;
    for (int e = 0; e < NEXP; ++e) {
      if (e == b0) continue;
      if (s_logit[e] > v1) { v1 = s_logit[e]; b1 = e; }
    }
    sel_flat[2 * n]     = b0;  score_flat[2 * n]     = 1.f / (1.f + expf(-v0));
    sel_flat[2 * n + 1] = b1;  score_flat[2 * n + 1] = 1.f / (1.f + expf(-v1));
    atomicAdd(&counts[b0], 1);
    atomicAdd(&counts[b1], 1);
  }
}

// ---------------- plan: offsets + tile descriptors ----------------
__global__ void plan_kernel(const int* __restrict__ counts, int* __restrict__ offsets,
                            int* __restrict__ cursors, int4* __restrict__ desc,
                            int* __restrict__ n_tiles) {
  if (threadIdx.x == 0 && blockIdx.x == 0) {
    int off = 0, nt = 0;
    for (int e = 0; e < NEXP; ++e) {
      offsets[e] = off; cursors[e] = 0;
      int c = counts[e];
      for (int t = 0; t < c; t += BM) {
        int4 d; d.x = e; d.y = off + t; d.z = (c - t < BM) ? (c - t) : BM; d.w = 0;
        desc[nt++] = d;
      }
      off += c;
    }
    for (int t = 0; t < N_TOK; t += BM) {   // shared expert = expert 8
      int4 d; d.x = NEXP; d.y = NSLOT + t; d.z = BM; d.w = 0;
      desc[nt++] = d;
    }
    *n_tiles = nt;
  }
}

// ---------------- scatter slots by expert ----------------
__global__ __launch_bounds__(256) void scatter_kernel(const int* __restrict__ sel_flat,
                                                      const float* __restrict__ score_flat,
                                                      const int* __restrict__ offsets,
                                                      int* __restrict__ cursors,
                                                      int* __restrict__ slot_token,
                                                      float* __restrict__ slot_score) {
  int i = blockIdx.x * 256 + threadIdx.x;
  if (i < NSLOT) {
    int e = sel_flat[i];
    int pos = offsets[e] + atomicAdd(&cursors[e], 1);
    slot_token[pos] = i >> 1;
    slot_score[pos] = score_flat[i];
  } else if (i < TSLOT) {
    slot_token[i] = i - NSLOT;
    slot_score[i] = 1.0f;
  }
}

// ---------------- build scaled routed_x (bf16) ----------------
__global__ __launch_bounds__(256) void build_rx_kernel(const float* __restrict__ x,
                                                       const int* __restrict__ slot_token,
                                                       const float* __restrict__ slot_score,
                                                       u16* __restrict__ rx) {
  int s = blockIdx.x;
  int t = slot_token[s];
  float sc = slot_score[s];
  const float4* xr = (const float4*)(x + (size_t)t * DIM_);
  u16* o = rx + (size_t)s * DIM_;
  for (int c = threadIdx.x; c < DIM_ / 4; c += 256) {
    float4 v = xr[c];
    ushort4 u;
    u.x = f2b(v.x * sc); u.y = f2b(v.y * sc); u.z = f2b(v.z * sc); u.w = f2b(v.w * sc);
    ((ushort4*)o)[c] = u;
  }
}

// ---------------- GEMM 1: h = silu(rx @ w1^T) * (rx @ w3^T) ----------------
__global__ __launch_bounds__(256) void gemm1_kernel(const u16* __restrict__ rx,
                                                    const u16* __restrict__ w1b,
                                                    const u16* __restrict__ w3b,
                                                    const u16* __restrict__ sw1b,
                                                    const u16* __restrict__ sw3b,
                                                    u16* __restrict__ h,
                                                    const int4* __restrict__ desc,
                                                    const int* __restrict__ n_tiles) {
  if ((int)blockIdx.x >= *n_tiles) return;
  int4 d = desc[blockIdx.x];
  int e = d.x, m0 = d.y, mcnt = d.z;
  int n0 = blockIdx.y * BN;
  const u16* W1 = (e < NEXP) ? w1b + (size_t)e * HID_ * DIM_ : sw1b;
  const u16* W3 = (e < NEXP) ? w3b + (size_t)e * HID_ * DIM_ : sw3b;

  __shared__ u16 As[BM][LDA];
  __shared__ u16 B1s[BN][LDA];
  __shared__ u16 B3s[BN][LDA];

  int tid = threadIdx.x;
  int lane = tid & 63, wid = tid >> 6;
  int wm = (wid >> 1) * 64, wn = (wid & 1) * 32;

  f32x4 acc1[4][2], acc3[4][2];
#pragma unroll
  for (int i = 0; i < 4; ++i)
#pragma unroll
    for (int j = 0; j < 2; ++j) { acc1[i][j] = (f32x4)(0.f); acc3[i][j] = (f32x4)(0.f); }

  int lrow = lane & 15, lk = (lane >> 4) * 8;

  for (int k0 = 0; k0 < DIM_; k0 += BK) {
#pragma unroll
    for (int c = 0; c < 2; ++c) {             // A: 128x32
      int chunk = tid + c * 256;
      int row = chunk >> 2, col = (chunk & 3) * 8;
      int4 v = {0, 0, 0, 0};
      if (row < mcnt) v = *(const int4*)(rx + (size_t)(m0 + row) * DIM_ + k0 + col);
      *(int4*)(&As[row][col]) = v;
    }
    {                                         // B1/B3: 64x32 each
      int row = tid >> 2, col = (tid & 3) * 8;
      *(int4*)(&B1s[row][col]) = *(const int4*)(W1 + (size_t)(n0 + row) * DIM_ + k0 + col);
      *(int4*)(&B3s[row][col]) = *(const int4*)(W3 + (size_t)(n0 + row) * DIM_ + k0 + col);
    }
    __syncthreads();
    bf16x8 af[4], b1f[2], b3f[2];
#pragma unroll
    for (int i = 0; i < 4; ++i) af[i] = *(const bf16x8*)(&As[wm + i * 16 + lrow][lk]);
#pragma unroll
    for (int j = 0; j < 2; ++j) {
      b1f[j] = *(const bf16x8*)(&B1s[wn + j * 16 + lrow][lk]);
      b3f[j] = *(const bf16x8*)(&B3s[wn + j * 16 + lrow][lk]);
    }
#pragma unroll
    for (int i = 0; i < 4; ++i)
#pragma unroll
      for (int j = 0; j < 2; ++j) {
        acc1[i][j] = __builtin_amdgcn_mfma_f32_16x16x32_bf16(af[i], b1f[j], acc1[i][j], 0, 0, 0);
        acc3[i][j] = __builtin_amdgcn_mfma_f32_16x16x32_bf16(af[i], b3f[j], acc3[i][j], 0, 0, 0);
      }
    __syncthreads();
  }

  int lcol = lane & 15, lrow4 = (lane >> 4) * 4;
#pragma unroll
  for (int i = 0; i < 4; ++i)
#pragma unroll
    for (int j = 0; j < 2; ++j)
#pragma unroll
      for (int r = 0; r < 4; ++r) {
        int m = wm + i * 16 + lrow4 + r;
        if (m < mcnt) {
          int n = n0 + wn + j * 16 + lcol;
          float g1 = acc1[i][j][r], g3 = acc3[i][j][r];
          float hv = (g1 / (1.f + __expf(-g1))) * g3;
          h[(size_t)(m0 + m) * HID_ + n] = f2b(hv);
        }
      }
}

// ---------------- GEMM 2: out[token] += h @ w2^T ----------------
__global__ __launch_bounds__(256) void gemm2_kernel(const u16* __restrict__ h,
                                                    const u16* __restrict__ w2b,
                                                    const u16* __restrict__ sw2b,
                                                    const int* __restrict__ slot_token,
                                                    float* __restrict__ out,
                                                    const int4* __restrict__ desc,
                                                    const int* __restrict__ n_tiles) {
  if ((int)blockIdx.x >= *n_tiles) return;
  int4 d = desc[blockIdx.x];
  int e = d.x, m0 = d.y, mcnt = d.z;
  int n0 = blockIdx.y * BN;
  const u16* W2 = (e < NEXP) ? w2b + (size_t)e * DIM_ * HID_ : sw2b;

  __shared__ u16 As[BM][LDA];
  __shared__ u16 Bs[BN][LDA];

  int tid = threadIdx.x;
  int lane = tid & 63, wid = tid >> 6;
  int wm = (wid >> 1) * 64, wn = (wid & 1) * 32;

  f32x4 acc[4][2];
#pragma unroll
  for (int i = 0; i < 4; ++i)
#pragma unroll
    for (int j = 0; j < 2; ++j) acc[i][j] = (f32x4)(0.f);

  int lrow = lane & 15, lk = (lane >> 4) * 8;

  for (int k0 = 0; k0 < HID_; k0 += BK) {
#pragma unroll
    for (int c = 0; c < 2; ++c) {
      int chunk = tid + c * 256;
      int row = chunk >> 2, col = (chunk & 3) * 8;
      int4 v = {0, 0, 0, 0};
      if (row < mcnt) v = *(const int4*)(h + (size_t)(m0 + row) * HID_ + k0 + col);
      *(int4*)(&As[row][col]) = v;
    }
    {
      int row = tid >> 2, col = (tid & 3) * 8;
      *(int4*)(&Bs[row][col]) = *(const int4*)(W2 + (size_t)(n0 + row) * HID_ + k0 + col);
    }
    __syncthreads();
    bf16x8 af[4], bf[2];
#pragma unroll
    for (int i = 0; i < 4; ++i) af[i] = *(const bf16x8*)(&As[wm + i * 16 + lrow][lk]);
#pragma unroll
    for (int j = 0; j < 2; ++j) bf[j] = *(const bf16x8*)(&Bs[wn + j * 16 + lrow][lk]);
#pragma unroll
    for (int i = 0; i < 4; ++i)
#pragma unroll
      for (int j = 0; j < 2; ++j)
        acc[i][j] = __builtin_amdgcn_mfma_f32_16x16x32_bf16(af[i], bf[j], acc[i][j], 0, 0, 0);
    __syncthreads();
  }

  int lcol = lane & 15, lrow4 = (lane >> 4) * 4;
#pragma unroll
  for (int i = 0; i < 4; ++i)
#pragma unroll
    for (int j = 0; j < 2; ++j)
#pragma unroll
      for (int r = 0; r < 4; ++r) {
        int m = wm + i * 16 + lrow4 + r;
        if (m < mcnt) {
          int tok = slot_token[m0 + m];
          int n = n0 + wn + j * 16 + lcol;
          atomicAdd(&out[(size_t)tok * DIM_ + n], acc[i][j][r]);
        }
      }
}

// ---------------- host launcher ----------------
extern "C" void kernel_launch(void* const* d_in, const int* in_sizes, int n_in,
                              void* d_out, int out_size, void* d_ws, size_t ws_size,
                              hipStream_t stream) {
  const float* x      = (const float*)d_in[0];
  const float* gate_w = (const float*)d_in[1];
  const float* w1     = (const float*)d_in[2];
  const float* w2     = (const float*)d_in[3];
  const float* w3     = (const float*)d_in[4];
  const float* sw1    = (const float*)d_in[5];
  const float* sw2    = (const float*)d_in[6];
  const float* sw3    = (const float*)d_in[7];
  float* out = (float*)d_out;

  char* ws = (char*)d_ws;
  size_t off = 0;
  auto alloc = [&](size_t bytes) -> void* {
    void* p = ws + off;
    off = (off + bytes + 255) & ~(size_t)255;
    return p;
  };
  const size_t WEXP = (size_t)NEXP * HID_ * DIM_;   // 16.78M elems
  const size_t WSH  = (size_t)HID_ * DIM_;          // 2.1M elems
  u16* w1b  = (u16*)alloc(WEXP * 2);
  u16* w3b  = (u16*)alloc(WEXP * 2);
  u16* w2b  = (u16*)alloc(WEXP * 2);
  u16* sw1b = (u16*)alloc(WSH * 2);
  u16* sw3b = (u16*)alloc(WSH * 2);
  u16* sw2b = (u16*)alloc(WSH * 2);
  u16* rx   = (u16*)alloc((size_t)TSLOT * DIM_ * 2);
  u16* hbuf = (u16*)alloc((size_t)TSLOT * HID_ * 2);
  int* slot_token   = (int*)alloc(TSLOT * 4);
  float* slot_score = (float*)alloc(TSLOT * 4);
  int* sel_flat     = (int*)alloc(NSLOT * 4);
  float* score_flat = (float*)alloc(NSLOT * 4);
  int* counts  = (int*)alloc(64);
  int* offsets = (int*)alloc(64);
  int* cursors = (int*)alloc(64);
  int* n_tiles = (int*)alloc(64);
  int4* desc   = (int4*)alloc(64 * sizeof(int4));

  hipMemsetAsync(out, 0, (size_t)out_size * sizeof(float), stream);
  hipMemsetAsync(counts, 0, 64, stream);

  cvt_kernel<<<2048, 256, 0, stream>>>(w1, w1b, (int)(WEXP / 4));
  cvt_kernel<<<2048, 256, 0, stream>>>(w3, w3b, (int)(WEXP / 4));
  cvt_kernel<<<2048, 256, 0, stream>>>(w2, w2b, (int)(WEXP / 4));
  cvt_kernel<<<2048, 256, 0, stream>>>(sw1, sw1b, (int)(WSH / 4));
  cvt_kernel<<<2048, 256, 0, stream>>>(sw3, sw3b, (int)(WSH / 4));
  cvt_kernel<<<2048, 256, 0, stream>>>(sw2, sw2b, (int)(WSH / 4));

  router_kernel<<<N_TOK, 256, 0, stream>>>(x, gate_w, sel_flat, score_flat, counts);
  plan_kernel<<<1, 64, 0, stream>>>(counts, offsets, cursors, desc, n_tiles);
  scatter_kernel<<<TSLOT / 256, 256, 0, stream>>>(sel_flat, score_flat, offsets, cursors,
                                                  slot_token, slot_score);
  build_rx_kernel<<<TSLOT, 256, 0, stream>>>(x, slot_token, slot_score, rx);

  dim3 g1(MAX_TILES, HID_ / BN);
  gemm1_kernel<<<g1, 256, 0, stream>>>(rx, w1b, w3b, sw1b, sw3b, hbuf, desc, n_tiles);
  dim3 g2(MAX_TILES, DIM_ / BN);
  gemm2_kernel<<<g2, 256, 0, stream>>>(hbuf, w2b, sw2b, slot_token, out, desc, n_tiles);
}

// Round 2
// 336.148 us; speedup vs baseline: 1.2476x; 1.2476x over previous
//
#include <hip/hip_runtime.h>
#include <hip/hip_bf16.h>

#define N_TOK 2048
#define DIM_  2048
#define HID_  1024
#define NEXP  8
#define NSLOT 4096          // N_TOK * K
#define TSLOT 6144          // + shared-expert slots
#define BM 128
#define BK 32
#define MAX_TILES 56

typedef unsigned short u16;
typedef __attribute__((ext_vector_type(4))) float f32x4;
typedef __attribute__((ext_vector_type(8))) __bf16 bf16x8;

static __device__ __forceinline__ u16 f2b(float f) {
  unsigned u = __builtin_bit_cast(unsigned, f);
  u += 0x7fffu + ((u >> 16) & 1u);   // RNE
  return (u16)(u >> 16);
}
static __device__ __forceinline__ float b2f(u16 v) {
  return __builtin_bit_cast(float, (unsigned)v << 16);
}
// async global->LDS, 16B per lane. lds ptr must be wave-uniform (HW adds lane*16).
static __device__ __forceinline__ void gld16(const u16* g, u16* l) {
  __builtin_amdgcn_global_load_lds(
      (const __attribute__((address_space(1))) unsigned int*)g,
      (__attribute__((address_space(3))) unsigned int*)l, 16, 0, 0);
}

// ---------------- fused fp32 -> bf16 convert of all 6 weight tensors ----------------
__global__ __launch_bounds__(256) void cvt_all_kernel(
    const float* __restrict__ w1, const float* __restrict__ w2, const float* __restrict__ w3,
    const float* __restrict__ s1, const float* __restrict__ s2, const float* __restrict__ s3,
    u16* __restrict__ w1b, u16* __restrict__ w2b, u16* __restrict__ w3b,
    u16* __restrict__ s1b, u16* __restrict__ s2b, u16* __restrict__ s3b) {
  const int CE = (NEXP * HID_ * DIM_) / 4;   // float4 chunks per expert tensor
  const int CS = (HID_ * DIM_) / 4;
  const long total = 3L * CE + 3L * CS;
  for (long i = blockIdx.x * 256L + threadIdx.x; i < total; i += gridDim.x * 256L) {
    const float* s; u16* d; long o = i;
    if (o < CE) { s = w1; d = w1b; }
    else if ((o -= CE) < CE) { s = w2; d = w2b; }
    else if ((o -= CE) < CE) { s = w3; d = w3b; }
    else if ((o -= CE) < CS) { s = s1; d = s1b; }
    else if ((o -= CS) < CS) { s = s2; d = s2b; }
    else { o -= CS; s = s3; d = s3b; }
    float4 v = ((const float4*)s)[o];
    ushort4 u;
    u.x = f2b(v.x); u.y = f2b(v.y); u.z = f2b(v.z); u.w = f2b(v.w);
    ((ushort4*)d)[o] = u;
  }
}

// ---------------- router: logits, top-2, counts ----------------
__global__ __launch_bounds__(256) void router_kernel(const float* __restrict__ x,
                                                     const float* __restrict__ gw,
                                                     int* __restrict__ sel_flat,
                                                     float* __restrict__ score_flat,
                                                     int* __restrict__ counts) {
  int n = blockIdx.x;
  const float* xr = x + (size_t)n * DIM_;
  int lane = threadIdx.x & 63, wid = threadIdx.x >> 6;
  __shared__ float s_logit[NEXP];
#pragma unroll
  for (int ee = 0; ee < 2; ++ee) {
    int e = wid * 2 + ee;
    const float* g = gw + (size_t)e * DIM_;
    float p = 0.f;
    for (int d = lane; d < DIM_; d += 64) p += xr[d] * g[d];
#pragma unroll
    for (int off = 32; off; off >>= 1) p += __shfl_down(p, off, 64);
    if (lane == 0) s_logit[e] = p;
  }
  __syncthreads();
  if (threadIdx.x == 0) {
    int b0 = 0; float v0 = s_logit[0];
    for (int e = 1; e < NEXP; ++e) if (s_logit[e] > v0) { v0 = s_logit[e]; b0 = e; }
    int b1 = -1; float v1 = -1e30f;
    for (int e = 0; e < NEXP; ++e) {
      if (e == b0) continue;
      if (s_logit[e] > v1) { v1 = s_logit[e]; b1 = e; }
    }
    sel_flat[2 * n]     = b0;  score_flat[2 * n]     = 1.f / (1.f + expf(-v0));
    sel_flat[2 * n + 1] = b1;  score_flat[2 * n + 1] = 1.f / (1.f + expf(-v1));
    atomicAdd(&counts[b0], 1);
    atomicAdd(&counts[b1], 1);
  }
}

// ---------------- plan: offsets + tile descriptors ----------------
__global__ void plan_kernel(const int* __restrict__ counts, int* __restrict__ offsets,
                            int* __restrict__ cursors, int4* __restrict__ desc,
                            int* __restrict__ n_tiles) {
  if (threadIdx.x == 0 && blockIdx.x == 0) {
    int off = 0, nt = 0;
    for (int e = 0; e < NEXP; ++e) {
      offsets[e] = off; cursors[e] = 0;
      int c = counts[e];
      for (int t = 0; t < c; t += BM) {
        int4 d; d.x = e; d.y = off + t; d.z = (c - t < BM) ? (c - t) : BM; d.w = 0;
        desc[nt++] = d;
      }
      off += c;
    }
    for (int t = 0; t < N_TOK; t += BM) {   // shared expert = expert 8
      int4 d; d.x = NEXP; d.y = NSLOT + t; d.z = BM; d.w = 0;
      desc[nt++] = d;
    }
    *n_tiles = nt;
  }
}

// ---------------- scatter slots by expert ----------------
__global__ __launch_bounds__(256) void scatter_kernel(const int* __restrict__ sel_flat,
                                                      const float* __restrict__ score_flat,
                                                      const int* __restrict__ offsets,
                                                      int* __restrict__ cursors,
                                                      int* __restrict__ slot_token,
                                                      float* __restrict__ slot_score,
                                                      int* __restrict__ slot_pos) {
  int i = blockIdx.x * 256 + threadIdx.x;
  if (i < NSLOT) {
    int e = sel_flat[i];
    int pos = offsets[e] + atomicAdd(&cursors[e], 1);
    slot_token[pos] = i >> 1;
    slot_score[pos] = score_flat[i];
    slot_pos[i] = pos;                 // inverse map for the combine pass
  } else if (i < TSLOT) {
    slot_token[i] = i - NSLOT;
    slot_score[i] = 1.0f;
  }
}

// ---------------- build scaled routed_x (bf16) ----------------
__global__ __launch_bounds__(256) void build_rx_kernel(const float* __restrict__ x,
                                                       const int* __restrict__ slot_token,
                                                       const float* __restrict__ slot_score,
                                                       u16* __restrict__ rx) {
  int s = blockIdx.x;
  int t = slot_token[s];
  float sc = slot_score[s];
  const float4* xr = (const float4*)(x + (size_t)t * DIM_);
  u16* o = rx + (size_t)s * DIM_;
  for (int c = threadIdx.x; c < DIM_ / 4; c += 256) {
    float4 v = xr[c];
    ushort4 u;
    u.x = f2b(v.x * sc); u.y = f2b(v.y * sc); u.z = f2b(v.z * sc); u.w = f2b(v.w * sc);
    ((ushort4*)o)[c] = u;
  }
}

// ---------------- GEMM 1: h = silu(rx @ w1^T) * (rx @ w3^T) ----------------
// 128x(64+64) tile, 4 waves each 64x32 per matrix, global_load_lds staging.
__global__ __launch_bounds__(256) void gemm1_kernel(const u16* __restrict__ rx,
                                                    const u16* __restrict__ w1b,
                                                    const u16* __restrict__ w3b,
                                                    const u16* __restrict__ sw1b,
                                                    const u16* __restrict__ sw3b,
                                                    u16* __restrict__ h,
                                                    const int4* __restrict__ desc,
                                                    const int* __restrict__ n_tiles) {
  if ((int)blockIdx.x >= *n_tiles) return;
  int4 dd = desc[blockIdx.x];
  int e = dd.x, m0 = dd.y, mcnt = dd.z;
  int n0 = blockIdx.y * 64;
  const u16* W1 = (e < NEXP) ? w1b + (size_t)e * HID_ * DIM_ : sw1b;
  const u16* W3 = (e < NEXP) ? w3b + (size_t)e * HID_ * DIM_ : sw3b;

  __shared__ __align__(16) u16 As[BM * BK];      // 8 KB, linear
  __shared__ __align__(16) u16 B1s[64 * BK];     // 4 KB
  __shared__ __align__(16) u16 B3s[64 * BK];     // 4 KB

  int tid = threadIdx.x, lane = tid & 63, wid = tid >> 6;
  int wm = (wid >> 1) * 64, wn = (wid & 1) * 32;
  int lrow = lane & 15, lk = (lane >> 4) * 8;

  // staging addresses: chunk c covers row c>>2, cols (c&3)*8 .. +7
  int colA = (tid & 3) * 8;
  int r0 = min(tid >> 2, mcnt - 1);            // clamp OOB rows (results masked later)
  int r1 = min((tid >> 2) + 64, mcnt - 1);
  const u16* gA0 = rx + (size_t)(m0 + r0) * DIM_ + colA;
  const u16* gA1 = rx + (size_t)(m0 + r1) * DIM_ + colA;
  const u16* gB1 = W1 + (size_t)(n0 + (tid >> 2)) * DIM_ + colA;
  const u16* gB3 = W3 + (size_t)(n0 + (tid >> 2)) * DIM_ + colA;
  u16* lA0 = As + wid * 512;                   // wave-uniform LDS bases (elems; 1 KB/wave)
  u16* lA1 = As + 2048 + wid * 512;
  u16* lB1 = B1s + wid * 512;
  u16* lB3 = B3s + wid * 512;

  f32x4 acc1[4][2], acc3[4][2];
#pragma unroll
  for (int i = 0; i < 4; ++i)
#pragma unroll
    for (int j = 0; j < 2; ++j) { acc1[i][j] = (f32x4)(0.f); acc3[i][j] = (f32x4)(0.f); }

  for (int k0 = 0; k0 < DIM_; k0 += BK) {
    gld16(gA0 + k0, lA0);
    gld16(gA1 + k0, lA1);
    gld16(gB1 + k0, lB1);
    gld16(gB3 + k0, lB3);
    __syncthreads();                            // drains vmcnt -> LDS ready
    bf16x8 af[4], b1f[2], b3f[2];
#pragma unroll
    for (int i = 0; i < 4; ++i)
      af[i] = *(const bf16x8*)(As + (wm + i * 16 + lrow) * BK + lk);
#pragma unroll
    for (int j = 0; j < 2; ++j) {
      b1f[j] = *(const bf16x8*)(B1s + (wn + j * 16 + lrow) * BK + lk);
      b3f[j] = *(const bf16x8*)(B3s + (wn + j * 16 + lrow) * BK + lk);
    }
#pragma unroll
    for (int i = 0; i < 4; ++i)
#pragma unroll
      for (int j = 0; j < 2; ++j) {
        acc1[i][j] = __builtin_amdgcn_mfma_f32_16x16x32_bf16(af[i], b1f[j], acc1[i][j], 0, 0, 0);
        acc3[i][j] = __builtin_amdgcn_mfma_f32_16x16x32_bf16(af[i], b3f[j], acc3[i][j], 0, 0, 0);
      }
    __syncthreads();                            // all reads done before next stage
  }

  int lcol = lane & 15, lrow4 = (lane >> 4) * 4;
#pragma unroll
  for (int i = 0; i < 4; ++i)
#pragma unroll
    for (int j = 0; j < 2; ++j)
#pragma unroll
      for (int r = 0; r < 4; ++r) {
        int m = wm + i * 16 + lrow4 + r;
        if (m < mcnt) {
          int n = n0 + wn + j * 16 + lcol;
          float g1 = acc1[i][j][r], g3 = acc3[i][j][r];
          float hv = (g1 / (1.f + __expf(-g1))) * g3;
          h[(size_t)(m0 + m) * HID_ + n] = f2b(hv);
        }
      }
}

// ---------------- GEMM 2: h2[slot] = h @ w2^T (bf16 store, no atomics) ----------------
// 128x128 tile, 4 waves each 64x64 (m97 geometry).
__global__ __launch_bounds__(256) void gemm2_kernel(const u16* __restrict__ h,
                                                    const u16* __restrict__ w2b,
                                                    const u16* __restrict__ sw2b,
                                                    u16* __restrict__ h2,
                                                    const int4* __restrict__ desc,
                                                    const int* __restrict__ n_tiles) {
  if ((int)blockIdx.x >= *n_tiles) return;
  int4 dd = desc[blockIdx.x];
  int e = dd.x, m0 = dd.y, mcnt = dd.z;
  int n0 = blockIdx.y * 128;
  const u16* W2 = (e < NEXP) ? w2b + (size_t)e * DIM_ * HID_ : sw2b;

  __shared__ __align__(16) u16 As[BM * BK];     // 8 KB
  __shared__ __align__(16) u16 Bs[BM * BK];     // 8 KB

  int tid = threadIdx.x, lane = tid & 63, wid = tid >> 6;
  int wm = (wid >> 1) * 64, wn = (wid & 1) * 64;
  int lrow = lane & 15, lk = (lane >> 4) * 8;

  int colA = (tid & 3) * 8;
  int r0 = min(tid >> 2, mcnt - 1);
  int r1 = min((tid >> 2) + 64, mcnt - 1);
  const u16* gA0 = h + (size_t)(m0 + r0) * HID_ + colA;
  const u16* gA1 = h + (size_t)(m0 + r1) * HID_ + colA;
  const u16* gB0 = W2 + (size_t)(n0 + (tid >> 2)) * HID_ + colA;
  const u16* gB1 = W2 + (size_t)(n0 + (tid >> 2) + 64) * HID_ + colA;
  u16* lA0 = As + wid * 512;
  u16* lA1 = As + 2048 + wid * 512;
  u16* lB0 = Bs + wid * 512;
  u16* lB1 = Bs + 2048 + wid * 512;

  f32x4 acc[4][4];
#pragma unroll
  for (int i = 0; i < 4; ++i)
#pragma unroll
    for (int j = 0; j < 4; ++j) acc[i][j] = (f32x4)(0.f);

  for (int k0 = 0; k0 < HID_; k0 += BK) {
    gld16(gA0 + k0, lA0);
    gld16(gA1 + k0, lA1);
    gld16(gB0 + k0, lB0);
    gld16(gB1 + k0, lB1);
    __syncthreads();
    bf16x8 af[4], bf[4];
#pragma unroll
    for (int i = 0; i < 4; ++i)
      af[i] = *(const bf16x8*)(As + (wm + i * 16 + lrow) * BK + lk);
#pragma unroll
    for (int j = 0; j < 4; ++j)
      bf[j] = *(const bf16x8*)(Bs + (wn + j * 16 + lrow) * BK + lk);
#pragma unroll
    for (int i = 0; i < 4; ++i)
#pragma unroll
      for (int j = 0; j < 4; ++j)
        acc[i][j] = __builtin_amdgcn_mfma_f32_16x16x32_bf16(af[i], bf[j], acc[i][j], 0, 0, 0);
    __syncthreads();
  }

  int lcol = lane & 15, lrow4 = (lane >> 4) * 4;
#pragma unroll
  for (int i = 0; i < 4; ++i)
#pragma unroll
    for (int j = 0; j < 4; ++j)
#pragma unroll
      for (int r = 0; r < 4; ++r) {
        int m = wm + i * 16 + lrow4 + r;
        if (m < mcnt) {
          int n = n0 + wn + j * 16 + lcol;
          h2[(size_t)(m0 + m) * DIM_ + n] = f2b(acc[i][j][r]);
        }
      }
}

// ---------------- combine: out[t] = h2[slot0(t)] + h2[slot1(t)] + h2[shared(t)] ----------------
__global__ __launch_bounds__(256) void combine_kernel(const u16* __restrict__ h2,
                                                      const int* __restrict__ slot_pos,
                                                      float* __restrict__ out) {
  int t = blockIdx.x;
  int s0 = slot_pos[2 * t], s1 = slot_pos[2 * t + 1];
  const ushort4* p0 = (const ushort4*)(h2 + (size_t)s0 * DIM_);
  const ushort4* p1 = (const ushort4*)(h2 + (size_t)s1 * DIM_);
  const ushort4* p2 = (const ushort4*)(h2 + (size_t)(NSLOT + t) * DIM_);
  float4* o = (float4*)(out + (size_t)t * DIM_);
  for (int c = threadIdx.x; c < DIM_ / 4; c += 256) {
    ushort4 a = p0[c], b = p1[c], s = p2[c];
    float4 v;
    v.x = b2f(a.x) + b2f(b.x) + b2f(s.x);
    v.y = b2f(a.y) + b2f(b.y) + b2f(s.y);
    v.z = b2f(a.z) + b2f(b.z) + b2f(s.z);
    v.w = b2f(a.w) + b2f(b.w) + b2f(s.w);
    o[c] = v;
  }
}

// ---------------- host launcher ----------------
extern "C" void kernel_launch(void* const* d_in, const int* in_sizes, int n_in,
                              void* d_out, int out_size, void* d_ws, size_t ws_size,
                              hipStream_t stream) {
  const float* x      = (const float*)d_in[0];
  const float* gate_w = (const float*)d_in[1];
  const float* w1     = (const float*)d_in[2];
  const float* w2     = (const float*)d_in[3];
  const float* w3     = (const float*)d_in[4];
  const float* sw1    = (const float*)d_in[5];
  const float* sw2    = (const float*)d_in[6];
  const float* sw3    = (const float*)d_in[7];
  float* out = (float*)d_out;

  char* ws = (char*)d_ws;
  size_t off = 0;
  auto alloc = [&](size_t bytes) -> void* {
    void* p = ws + off;
    off = (off + bytes + 255) & ~(size_t)255;
    return p;
  };
  const size_t WEXP = (size_t)NEXP * HID_ * DIM_;
  const size_t WSH  = (size_t)HID_ * DIM_;
  u16* w1b  = (u16*)alloc(WEXP * 2);
  u16* w3b  = (u16*)alloc(WEXP * 2);
  u16* w2b  = (u16*)alloc(WEXP * 2);
  u16* sw1b = (u16*)alloc(WSH * 2);
  u16* sw3b = (u16*)alloc(WSH * 2);
  u16* sw2b = (u16*)alloc(WSH * 2);
  u16* rx   = (u16*)alloc((size_t)TSLOT * DIM_ * 2);
  u16* hbuf = (u16*)alloc((size_t)TSLOT * HID_ * 2);
  u16* h2   = (u16*)alloc((size_t)TSLOT * DIM_ * 2);
  int* slot_token   = (int*)alloc(TSLOT * 4);
  float* slot_score = (float*)alloc(TSLOT * 4);
  int* slot_pos     = (int*)alloc(NSLOT * 4);
  int* sel_flat     = (int*)alloc(NSLOT * 4);
  float* score_flat = (float*)alloc(NSLOT * 4);
  int* counts  = (int*)alloc(64);
  int* offsets = (int*)alloc(64);
  int* cursors = (int*)alloc(64);
  int* n_tiles = (int*)alloc(64);
  int4* desc   = (int4*)alloc(64 * sizeof(int4));

  hipMemsetAsync(counts, 0, 64, stream);

  cvt_all_kernel<<<2048, 256, 0, stream>>>(w1, w2, w3, sw1, sw2, sw3,
                                           w1b, w2b, w3b, sw1b, sw2b, sw3b);

  router_kernel<<<N_TOK, 256, 0, stream>>>(x, gate_w, sel_flat, score_flat, counts);
  plan_kernel<<<1, 64, 0, stream>>>(counts, offsets, cursors, desc, n_tiles);
  scatter_kernel<<<TSLOT / 256, 256, 0, stream>>>(sel_flat, score_flat, offsets, cursors,
                                                  slot_token, slot_score, slot_pos);
  build_rx_kernel<<<TSLOT, 256, 0, stream>>>(x, slot_token, slot_score, rx);

  dim3 g1(MAX_TILES, HID_ / 64);
  gemm1_kernel<<<g1, 256, 0, stream>>>(rx, w1b, w3b, sw1b, sw3b, hbuf, desc, n_tiles);
  dim3 g2(MAX_TILES, DIM_ / 128);
  gemm2_kernel<<<g2, 256, 0, stream>>>(hbuf, w2b, sw2b, h2, desc, n_tiles);
  combine_kernel<<<N_TOK, 256, 0, stream>>>(h2, slot_pos, out);
}